// Round 18
// baseline (5907.536 us; speedup 1.0000x reference)
//
#include <hip/hip_runtime.h>
#include <hip/hip_bf16.h>

#define DH 64
#define DM 256

typedef float f32x2 __attribute__((ext_vector_type(2)));

__device__ __forceinline__ f32x2 sp2(float s) { return (f32x2){s, s}; }
__device__ __forceinline__ f32x2 pkfma(f32x2 a, f32x2 b, f32x2 c) {
#if __has_builtin(__builtin_elementwise_fma)
    return __builtin_elementwise_fma(a, b, c);
#else
    f32x2 r; r.x = fmaf(a.x, b.x, c.x); r.y = fmaf(a.y, b.y, c.y); return r;
#endif
}

__device__ __forceinline__ float tanh_fast(float y) {
    float e = __expf(2.0f * y);
    return 1.0f - 2.0f / (e + 1.0f);
}
__device__ __forceinline__ float sigmoid_fast(float x) {
    return 1.0f / (1.0f + __expf(-x));
}

template <int CTRL, int RMASK>
__device__ __forceinline__ float dpp_term(float x) {
    int p = __builtin_amdgcn_update_dpp(0, __float_as_int(x), CTRL, RMASK, 0xf, false);
    return __int_as_float(p);
}
__device__ __forceinline__ float wave_sum63(float x) {
    x += dpp_term<0xB1,  0xf>(x);
    x += dpp_term<0x4E,  0xf>(x);
    x += dpp_term<0x141, 0xf>(x);
    x += dpp_term<0x140, 0xf>(x);
    x += dpp_term<0x142, 0xa>(x);
    x += dpp_term<0x143, 0xc>(x);
    return x;
}

// ---------------------------------------------------------------------------
// Kernel A: u[t][0..63] = phi[t]·thetaQ, u[t][64..127] = phi[t]·thetaK
// ---------------------------------------------------------------------------
__global__ __launch_bounds__(256) void proj_kernel(
    const float* __restrict__ phi,
    const float* __restrict__ thK,
    const float* __restrict__ thQ,
    float* __restrict__ u,
    int dphi)
{
    const int tid  = threadIdx.x;
    const int th32 = tid & 31;
    const int tt8  = tid >> 5;
    const int t0   = tt8 * 4;
    const int h0   = th32 * 4;
    const int T0   = blockIdx.x * 32;

    __shared__ float sPhiT[32][36];
    __shared__ float sThT[32][128];

    const int h   = tid >> 1;
    const int ko  = (tid & 1) * 16;
    const float* trow = (h < 64) ? (thQ + (size_t)h * dphi)
                                 : (thK + (size_t)(h - 64) * dphi);
    const int tr  = tid >> 3;
    const int k4p = (tid & 7) * 4;

    float4 pv, tv0, tv1, tv2, tv3;
    pv  = *(const float4*)&phi[(size_t)(T0 + tr) * dphi + k4p];
    tv0 = *(const float4*)&trow[ko + 0];
    tv1 = *(const float4*)&trow[ko + 4];
    tv2 = *(const float4*)&trow[ko + 8];
    tv3 = *(const float4*)&trow[ko + 12];

    float acc[4][4];
    #pragma unroll
    for (int i = 0; i < 4; ++i)
        #pragma unroll
        for (int jj = 0; jj < 4; ++jj) acc[i][jj] = 0.0f;

    const int NC = dphi / 32;
    for (int c = 0; c < NC; ++c) {
        __syncthreads();
        sPhiT[k4p + 0][tr] = pv.x;
        sPhiT[k4p + 1][tr] = pv.y;
        sPhiT[k4p + 2][tr] = pv.z;
        sPhiT[k4p + 3][tr] = pv.w;
        sThT[ko +  0][h] = tv0.x;  sThT[ko +  1][h] = tv0.y;
        sThT[ko +  2][h] = tv0.z;  sThT[ko +  3][h] = tv0.w;
        sThT[ko +  4][h] = tv1.x;  sThT[ko +  5][h] = tv1.y;
        sThT[ko +  6][h] = tv1.z;  sThT[ko +  7][h] = tv1.w;
        sThT[ko +  8][h] = tv2.x;  sThT[ko +  9][h] = tv2.y;
        sThT[ko + 10][h] = tv2.z;  sThT[ko + 11][h] = tv2.w;
        sThT[ko + 12][h] = tv3.x;  sThT[ko + 13][h] = tv3.y;
        sThT[ko + 14][h] = tv3.z;  sThT[ko + 15][h] = tv3.w;
        __syncthreads();
        if (c + 1 < NC) {
            const int kb = (c + 1) * 32;
            pv  = *(const float4*)&phi[(size_t)(T0 + tr) * dphi + kb + k4p];
            tv0 = *(const float4*)&trow[kb + ko + 0];
            tv1 = *(const float4*)&trow[kb + ko + 4];
            tv2 = *(const float4*)&trow[kb + ko + 8];
            tv3 = *(const float4*)&trow[kb + ko + 12];
        }
        #pragma unroll 8
        for (int k = 0; k < 32; ++k) {
            float4 ph = *(const float4*)&sPhiT[k][t0];
            float4 th = *(const float4*)&sThT[k][h0];
            acc[0][0] = fmaf(ph.x, th.x, acc[0][0]);
            acc[0][1] = fmaf(ph.x, th.y, acc[0][1]);
            acc[0][2] = fmaf(ph.x, th.z, acc[0][2]);
            acc[0][3] = fmaf(ph.x, th.w, acc[0][3]);
            acc[1][0] = fmaf(ph.y, th.x, acc[1][0]);
            acc[1][1] = fmaf(ph.y, th.y, acc[1][1]);
            acc[1][2] = fmaf(ph.y, th.z, acc[1][2]);
            acc[1][3] = fmaf(ph.y, th.w, acc[1][3]);
            acc[2][0] = fmaf(ph.z, th.x, acc[2][0]);
            acc[2][1] = fmaf(ph.z, th.y, acc[2][1]);
            acc[2][2] = fmaf(ph.z, th.z, acc[2][2]);
            acc[2][3] = fmaf(ph.z, th.w, acc[2][3]);
            acc[3][0] = fmaf(ph.w, th.x, acc[3][0]);
            acc[3][1] = fmaf(ph.w, th.y, acc[3][1]);
            acc[3][2] = fmaf(ph.w, th.z, acc[3][2]);
            acc[3][3] = fmaf(ph.w, th.w, acc[3][3]);
        }
    }
    #pragma unroll
    for (int i = 0; i < 4; ++i) {
        float4 o;
        o.x = acc[i][0]; o.y = acc[i][1]; o.z = acc[i][2]; o.w = acc[i][3];
        *(float4*)&u[(size_t)(T0 + t0 + i) * 128 + h0] = o;
    }
}

// ---------------------------------------------------------------------------
// Kernel A2: dd4[t] = { uk(t-1)·uk(t), uk(t-2)·uk(t), uk(t-3)·uk(t), 0 }
// ---------------------------------------------------------------------------
__global__ __launch_bounds__(256) void dots3_kernel(
    const float* __restrict__ u, float4* __restrict__ dd4, int T)
{
    const int t    = (blockIdx.x * 256 + threadIdx.x) >> 6;
    const int lane = threadIdx.x & 63;
    if (t >= T) return;
    float ukt = u[(size_t)t * 128 + 64 + lane];
    float k1 = (t >= 1) ? u[(size_t)(t - 1) * 128 + 64 + lane] : 0.f;
    float k2 = (t >= 2) ? u[(size_t)(t - 2) * 128 + 64 + lane] : 0.f;
    float k3 = (t >= 3) ? u[(size_t)(t - 3) * 128 + 64 + lane] : 0.f;
    float p1 = k1 * ukt, p2 = k2 * ukt, p3 = k3 * ukt;
    #pragma unroll
    for (int off = 32; off > 0; off >>= 1) {
        p1 += __shfl_xor(p1, off);
        p2 += __shfl_xor(p2, off);
        p3 += __shfl_xor(p3, off);
    }
    if (lane == 0) dd4[t] = make_float4(p1, p2, p3, 0.f);
}

// ---------------------------------------------------------------------------
// Kernel B: 4-wave k-only scan, redundant-column chain, TWO steps per
// barrier. Wave wv owns W1 rows [16wv,16wv+16) x cols [4lane,4lane+4);
// scalar state (b1/w2/b2, acts) redundant in all waves over cols
// [4lane,4lane+4) -> zp reduce fully in-wave (DPP + readlane). Per iter m:
// chain steps 2m, 2m+1 back-to-back (Gram-dot fixups vs W1(2m-2) base);
// off-chain UPD(e1(2m-2),e1(2m-1)) + MV(uk(2m+2),uk(2m+3)); ONE barrier.
// ---------------------------------------------------------------------------
__global__ __launch_bounds__(256, 1) void scan_k2(
    const float* __restrict__ u,       // [T][128]
    const float4* __restrict__ dd4g,   // [T]
    const float* __restrict__ W10,     // [64][256]
    const float* __restrict__ b10,     // [256]
    const float* __restrict__ W20,     // [256]
    const float* __restrict__ b20,
    const float* __restrict__ log_eta,
    float* __restrict__ e1s,           // [T][256]
    float* __restrict__ g2s,           // [T][256]
    float* __restrict__ dz2s,          // [T]
    int T)
{
    const int j    = threadIdx.x;
    const int lane = j & 63;
    const int wv   = j >> 6;
    const int uko  = 16 * wv;          // W1 row slice
    const int c0   = 4 * lane;         // column slice (same in all waves)

    __shared__ __align__(16) float  ubuf[2][64][68];     // 34 KB
    __shared__ __align__(16) float  pbuf[2][2][4][256];  // 16 KB
    __shared__ __align__(16) float4 dbuf[2][64];         // 2 KB

    const int NB = T >> 6;
    const int sl = j >> 2, qq = j & 3;

    // ---- prologue: stage block 0 ----
    {
        const float* src = u + (size_t)sl * 128 + 64 + qq * 16;
        #pragma unroll
        for (int k = 0; k < 4; ++k)
            *(float4*)&ubuf[0][sl][qq * 16 + k * 4] = *(const float4*)&src[k * 4];
        if (j < 64) dbuf[0][j] = dd4g[j];
    }

    // W1 tile: rows uko..uko+15, cols c0..c0+3
    f32x2 w1p[32];
    #pragma unroll
    for (int i = 0; i < 16; ++i) {
        float4 wr = *(const float4*)&W10[(uko + i) * DM + c0];
        w1p[2 * i]     = (f32x2){wr.x, wr.y};
        w1p[2 * i + 1] = (f32x2){wr.z, wr.w};
    }
    float4 b14 = *(const float4*)&b10[c0];
    f32x2 b1v0 = (f32x2){b14.x, b14.y}, b1v1 = (f32x2){b14.z, b14.w};
    float4 w24 = *(const float4*)&W20[c0];
    f32x2 w2v0 = (f32x2){w24.x, w24.y}, w2v1 = (f32x2){w24.z, w24.w};
    float b2  = b20[0];
    const float eta = __expf(log_eta[0]);

    f32x2 e1m2a = sp2(0.f), e1m2b = sp2(0.f);   // e1(2m-2)
    f32x2 e1m1a = sp2(0.f), e1m1b = sp2(0.f);   // e1(2m-1)

    __syncthreads();

#define MVS(usp, A0, A1) {                                                   \
        float4 ua_ = *(const float4*)&(usp)[0];                              \
        float4 ub_ = *(const float4*)&(usp)[4];                              \
        float4 uc_ = *(const float4*)&(usp)[8];                              \
        float4 ud_ = *(const float4*)&(usp)[12];                             \
        A0 = pkfma(sp2(ua_.x), w1p[0],  A0); A1 = pkfma(sp2(ua_.x), w1p[1],  A1); \
        A0 = pkfma(sp2(ua_.y), w1p[2],  A0); A1 = pkfma(sp2(ua_.y), w1p[3],  A1); \
        A0 = pkfma(sp2(ua_.z), w1p[4],  A0); A1 = pkfma(sp2(ua_.z), w1p[5],  A1); \
        A0 = pkfma(sp2(ua_.w), w1p[6],  A0); A1 = pkfma(sp2(ua_.w), w1p[7],  A1); \
        A0 = pkfma(sp2(ub_.x), w1p[8],  A0); A1 = pkfma(sp2(ub_.x), w1p[9],  A1); \
        A0 = pkfma(sp2(ub_.y), w1p[10], A0); A1 = pkfma(sp2(ub_.y), w1p[11], A1); \
        A0 = pkfma(sp2(ub_.z), w1p[12], A0); A1 = pkfma(sp2(ub_.z), w1p[13], A1); \
        A0 = pkfma(sp2(ub_.w), w1p[14], A0); A1 = pkfma(sp2(ub_.w), w1p[15], A1); \
        A0 = pkfma(sp2(uc_.x), w1p[16], A0); A1 = pkfma(sp2(uc_.x), w1p[17], A1); \
        A0 = pkfma(sp2(uc_.y), w1p[18], A0); A1 = pkfma(sp2(uc_.y), w1p[19], A1); \
        A0 = pkfma(sp2(uc_.z), w1p[20], A0); A1 = pkfma(sp2(uc_.z), w1p[21], A1); \
        A0 = pkfma(sp2(uc_.w), w1p[22], A0); A1 = pkfma(sp2(uc_.w), w1p[23], A1); \
        A0 = pkfma(sp2(ud_.x), w1p[24], A0); A1 = pkfma(sp2(ud_.x), w1p[25], A1); \
        A0 = pkfma(sp2(ud_.y), w1p[26], A0); A1 = pkfma(sp2(ud_.y), w1p[27], A1); \
        A0 = pkfma(sp2(ud_.z), w1p[28], A0); A1 = pkfma(sp2(ud_.z), w1p[29], A1); \
        A0 = pkfma(sp2(ud_.w), w1p[30], A0); A1 = pkfma(sp2(ud_.w), w1p[31], A1); \
    }

#define UPDS(usp, EA, EB) {                                                  \
        float4 ua_ = *(const float4*)&(usp)[0];                              \
        float4 ub_ = *(const float4*)&(usp)[4];                              \
        float4 uc_ = *(const float4*)&(usp)[8];                              \
        float4 ud_ = *(const float4*)&(usp)[12];                             \
        w1p[0]  = pkfma(sp2(-ua_.x), EA, w1p[0]);  w1p[1]  = pkfma(sp2(-ua_.x), EB, w1p[1]);  \
        w1p[2]  = pkfma(sp2(-ua_.y), EA, w1p[2]);  w1p[3]  = pkfma(sp2(-ua_.y), EB, w1p[3]);  \
        w1p[4]  = pkfma(sp2(-ua_.z), EA, w1p[4]);  w1p[5]  = pkfma(sp2(-ua_.z), EB, w1p[5]);  \
        w1p[6]  = pkfma(sp2(-ua_.w), EA, w1p[6]);  w1p[7]  = pkfma(sp2(-ua_.w), EB, w1p[7]);  \
        w1p[8]  = pkfma(sp2(-ub_.x), EA, w1p[8]);  w1p[9]  = pkfma(sp2(-ub_.x), EB, w1p[9]);  \
        w1p[10] = pkfma(sp2(-ub_.y), EA, w1p[10]); w1p[11] = pkfma(sp2(-ub_.y), EB, w1p[11]); \
        w1p[12] = pkfma(sp2(-ub_.z), EA, w1p[12]); w1p[13] = pkfma(sp2(-ub_.z), EB, w1p[13]); \
        w1p[14] = pkfma(sp2(-ub_.w), EA, w1p[14]); w1p[15] = pkfma(sp2(-ub_.w), EB, w1p[15]); \
        w1p[16] = pkfma(sp2(-uc_.x), EA, w1p[16]); w1p[17] = pkfma(sp2(-uc_.x), EB, w1p[17]); \
        w1p[18] = pkfma(sp2(-uc_.y), EA, w1p[18]); w1p[19] = pkfma(sp2(-uc_.y), EB, w1p[19]); \
        w1p[20] = pkfma(sp2(-uc_.z), EA, w1p[20]); w1p[21] = pkfma(sp2(-uc_.z), EB, w1p[21]); \
        w1p[22] = pkfma(sp2(-uc_.w), EA, w1p[22]); w1p[23] = pkfma(sp2(-uc_.w), EB, w1p[23]); \
        w1p[24] = pkfma(sp2(-ud_.x), EA, w1p[24]); w1p[25] = pkfma(sp2(-ud_.x), EB, w1p[25]); \
        w1p[26] = pkfma(sp2(-ud_.y), EA, w1p[26]); w1p[27] = pkfma(sp2(-ud_.y), EB, w1p[27]); \
        w1p[28] = pkfma(sp2(-ud_.z), EA, w1p[28]); w1p[29] = pkfma(sp2(-ud_.z), EB, w1p[29]); \
        w1p[30] = pkfma(sp2(-ud_.w), EA, w1p[30]); w1p[31] = pkfma(sp2(-ud_.w), EB, w1p[31]); \
    }

    // peel: P(0), P(1) from W1(0) = W10
    {
        #pragma unroll
        for (int s = 0; s < 2; ++s) {
            const float* us = &ubuf[0][s][uko];
            f32x2 a0 = sp2(0.f), a1 = sp2(0.f);
            MVS(us, a0, a1);
            float4 wk; wk.x = a0.x; wk.y = a0.y; wk.z = a1.x; wk.w = a1.y;
            *(float4*)&pbuf[0][s][wv][c0] = wk;
        }
    }
    __syncthreads();

    float4 st[4];
    float4 std4 = make_float4(0.f, 0.f, 0.f, 0.f);
    const int NIT = T >> 1;

    for (int m = 0; m < NIT; ++m) {
        const int t0 = 2 * m;
        const int r2 = t0 & 63;
        const int B  = t0 >> 6;
        const int bs = B & 1;
        const int pb = m & 1;

        // ---- early LDS reads (chain inputs) ----
        float4 P00 = *(const float4*)&pbuf[pb][0][0][c0];
        float4 P01 = *(const float4*)&pbuf[pb][0][1][c0];
        float4 P02 = *(const float4*)&pbuf[pb][0][2][c0];
        float4 P03 = *(const float4*)&pbuf[pb][0][3][c0];
        float4 P10 = *(const float4*)&pbuf[pb][1][0][c0];
        float4 P11 = *(const float4*)&pbuf[pb][1][1][c0];
        float4 P12 = *(const float4*)&pbuf[pb][1][2][c0];
        float4 P13 = *(const float4*)&pbuf[pb][1][3][c0];
        float4 dd0 = dbuf[bs][r2];
        float4 dd1 = dbuf[bs][r2 + 1];

        // ---- chain: step t0 ----
        f32x2 Pa0 = (f32x2){(P00.x + P01.x) + (P02.x + P03.x),
                            (P00.y + P01.y) + (P02.y + P03.y)};
        f32x2 Pb0 = (f32x2){(P00.z + P01.z) + (P02.z + P03.z),
                            (P00.w + P01.w) + (P02.w + P03.w)};
        f32x2 zka = Pa0 + b1v0 - sp2(dd0.y) * e1m2a - sp2(dd0.x) * e1m1a;
        f32x2 zkb = Pb0 + b1v1 - sp2(dd0.y) * e1m2b - sp2(dd0.x) * e1m1b;
        float z0 = zka.x, z1 = zka.y, z2 = zkb.x, z3 = zkb.y;
        float tk0 = tanh_fast(0.79788456f * z0 * fmaf(0.044715f, z0*z0, 1.f));
        float tk1 = tanh_fast(0.79788456f * z1 * fmaf(0.044715f, z1*z1, 1.f));
        float tk2 = tanh_fast(0.79788456f * z2 * fmaf(0.044715f, z2*z2, 1.f));
        float tk3 = tanh_fast(0.79788456f * z3 * fmaf(0.044715f, z3*z3, 1.f));
        f32x2 x2a0 = (f32x2){0.5f*z0*(1.f+tk0), 0.5f*z1*(1.f+tk1)};
        f32x2 x2b0 = (f32x2){0.5f*z2*(1.f+tk2), 0.5f*z3*(1.f+tk3)};
        float gb0 = 0.5f*z0*((1.f-tk0*tk0)*fmaf(0.1070322243f, z0*z0, 0.79788456f)) + 0.5f*(1.f+tk0);
        float gb1 = 0.5f*z1*((1.f-tk1*tk1)*fmaf(0.1070322243f, z1*z1, 0.79788456f)) + 0.5f*(1.f+tk1);
        float gb2 = 0.5f*z2*((1.f-tk2*tk2)*fmaf(0.1070322243f, z2*z2, 0.79788456f)) + 0.5f*(1.f+tk2);
        float gb3 = 0.5f*z3*((1.f-tk3*tk3)*fmaf(0.1070322243f, z3*z3, 0.79788456f)) + 0.5f*(1.f+tk3);
        f32x2 pr0 = x2a0 * w2v0;
        pr0 = pkfma(x2b0, w2v1, pr0);
        float red0 = wave_sum63(pr0.x + pr0.y);
        float zp0  = __int_as_float(__builtin_amdgcn_readlane(__float_as_int(red0), 63)) + b2;
        float pred0 = sigmoid_fast(zp0);
        float dZ20  = 2.f * pred0 * pred0 * (1.f - pred0);
        f32x2 ed0 = sp2(eta * dZ20);
        f32x2 e1_0a = ed0 * w2v0 * (f32x2){gb0, gb1};
        f32x2 e1_0b = ed0 * w2v1 * (f32x2){gb2, gb3};
        if (wv == 0) {
            float4 e1st; e1st.x = e1_0a.x; e1st.y = e1_0a.y; e1st.z = e1_0b.x; e1st.w = e1_0b.y;
            *(float4*)&e1s[(size_t)t0 * 256 + c0] = e1st;
            f32x2 g2a = sp2(dZ20) * x2a0, g2b = sp2(dZ20) * x2b0;
            float4 g2st; g2st.x = g2a.x; g2st.y = g2a.y; g2st.z = g2b.x; g2st.w = g2b.y;
            *(float4*)&g2s[(size_t)t0 * 256 + c0] = g2st;
            if (j == 0) dz2s[t0] = dZ20;
        }
        w2v0 = pkfma(sp2(-eta * dZ20), x2a0, w2v0);
        w2v1 = pkfma(sp2(-eta * dZ20), x2b0, w2v1);
        b2  -= eta * dZ20;
        b1v0 = b1v0 - e1_0a;
        b1v1 = b1v1 - e1_0b;

        // ---- chain: step t0+1 ----
        f32x2 Pa1 = (f32x2){(P10.x + P11.x) + (P12.x + P13.x),
                            (P10.y + P11.y) + (P12.y + P13.y)};
        f32x2 Pb1 = (f32x2){(P10.z + P11.z) + (P12.z + P13.z),
                            (P10.w + P11.w) + (P12.w + P13.w)};
        f32x2 zka1 = Pa1 + b1v0 - sp2(dd1.z) * e1m2a - sp2(dd1.y) * e1m1a - sp2(dd1.x) * e1_0a;
        f32x2 zkb1 = Pb1 + b1v1 - sp2(dd1.z) * e1m2b - sp2(dd1.y) * e1m1b - sp2(dd1.x) * e1_0b;
        float y0 = zka1.x, y1 = zka1.y, y2 = zkb1.x, y3 = zkb1.y;
        float sk0 = tanh_fast(0.79788456f * y0 * fmaf(0.044715f, y0*y0, 1.f));
        float sk1 = tanh_fast(0.79788456f * y1 * fmaf(0.044715f, y1*y1, 1.f));
        float sk2 = tanh_fast(0.79788456f * y2 * fmaf(0.044715f, y2*y2, 1.f));
        float sk3 = tanh_fast(0.79788456f * y3 * fmaf(0.044715f, y3*y3, 1.f));
        f32x2 x2a1 = (f32x2){0.5f*y0*(1.f+sk0), 0.5f*y1*(1.f+sk1)};
        f32x2 x2b1 = (f32x2){0.5f*y2*(1.f+sk2), 0.5f*y3*(1.f+sk3)};
        float hb0 = 0.5f*y0*((1.f-sk0*sk0)*fmaf(0.1070322243f, y0*y0, 0.79788456f)) + 0.5f*(1.f+sk0);
        float hb1 = 0.5f*y1*((1.f-sk1*sk1)*fmaf(0.1070322243f, y1*y1, 0.79788456f)) + 0.5f*(1.f+sk1);
        float hb2 = 0.5f*y2*((1.f-sk2*sk2)*fmaf(0.1070322243f, y2*y2, 0.79788456f)) + 0.5f*(1.f+sk2);
        float hb3 = 0.5f*y3*((1.f-sk3*sk3)*fmaf(0.1070322243f, y3*y3, 0.79788456f)) + 0.5f*(1.f+sk3);
        f32x2 pr1 = x2a1 * w2v0;
        pr1 = pkfma(x2b1, w2v1, pr1);
        float red1 = wave_sum63(pr1.x + pr1.y);
        float zp1  = __int_as_float(__builtin_amdgcn_readlane(__float_as_int(red1), 63)) + b2;
        float pred1 = sigmoid_fast(zp1);
        float dZ21  = 2.f * pred1 * pred1 * (1.f - pred1);
        f32x2 ed1 = sp2(eta * dZ21);
        f32x2 e1_1a = ed1 * w2v0 * (f32x2){hb0, hb1};
        f32x2 e1_1b = ed1 * w2v1 * (f32x2){hb2, hb3};
        if (wv == 0) {
            float4 e1st; e1st.x = e1_1a.x; e1st.y = e1_1a.y; e1st.z = e1_1b.x; e1st.w = e1_1b.y;
            *(float4*)&e1s[(size_t)(t0 + 1) * 256 + c0] = e1st;
            f32x2 g2a = sp2(dZ21) * x2a1, g2b = sp2(dZ21) * x2b1;
            float4 g2st; g2st.x = g2a.x; g2st.y = g2a.y; g2st.z = g2b.x; g2st.w = g2b.y;
            *(float4*)&g2s[(size_t)(t0 + 1) * 256 + c0] = g2st;
            if (j == 0) dz2s[t0 + 1] = dZ21;
        }
        w2v0 = pkfma(sp2(-eta * dZ21), x2a1, w2v0);
        w2v1 = pkfma(sp2(-eta * dZ21), x2b1, w2v1);
        b2  -= eta * dZ21;
        b1v0 = b1v0 - e1_1a;
        b1v1 = b1v1 - e1_1b;

        // ---- off-chain: UPD(e1(2m-2), e1(2m-1)) then MV(uk(2m+2), uk(2m+3)) ----
        {
            const int tA = (t0 >= 2) ? t0 - 2 : 0;
            const int tB = (t0 >= 1) ? t0 - 1 : 0;
            const float* uA = &ubuf[(tA >> 6) & 1][tA & 63][uko];
            const float* uB = &ubuf[(tB >> 6) & 1][tB & 63][uko];
            UPDS(uA, e1m2a, e1m2b);
            UPDS(uB, e1m1a, e1m1b);
            if (m + 1 < NIT) {
                const int tN0 = t0 + 2, tN1 = t0 + 3;
                const float* uN0 = &ubuf[(tN0 >> 6) & 1][tN0 & 63][uko];
                const float* uN1 = &ubuf[(tN1 >> 6) & 1][tN1 & 63][uko];
                f32x2 a0 = sp2(0.f), a1 = sp2(0.f);
                MVS(uN0, a0, a1);
                float4 wk; wk.x = a0.x; wk.y = a0.y; wk.z = a1.x; wk.w = a1.y;
                *(float4*)&pbuf[pb ^ 1][0][wv][c0] = wk;
                f32x2 c0v = sp2(0.f), c1v = sp2(0.f);
                MVS(uN1, c0v, c1v);
                float4 wk2; wk2.x = c0v.x; wk2.y = c0v.y; wk2.z = c1v.x; wk2.w = c1v.y;
                *(float4*)&pbuf[pb ^ 1][1][wv][c0] = wk2;
            }
        }

        // rotate e1 history
        e1m2a = e1_0a; e1m2b = e1_0b;
        e1m1a = e1_1a; e1m1b = e1_1b;

        // ---- bulk staging ----
        if (r2 == 0 && B + 1 < NB) {
            const float* src = u + (size_t)((B + 1) * 64 + sl) * 128 + 64 + qq * 16;
            #pragma unroll
            for (int k = 0; k < 4; ++k) st[k] = *(const float4*)&src[k * 4];
            if (j < 64) std4 = dd4g[(B + 1) * 64 + j];
        }
        if (r2 == 32 && B + 1 < NB) {
            #pragma unroll
            for (int k = 0; k < 4; ++k)
                *(float4*)&ubuf[bs ^ 1][sl][qq * 16 + k * 4] = st[k];
            if (j < 64) dbuf[bs ^ 1][j] = std4;
        }

        asm volatile("s_waitcnt lgkmcnt(0)" ::: "memory");
        __builtin_amdgcn_s_barrier();
        asm volatile("" ::: "memory");
    }
#undef MVS
#undef UPDS
}

// ---------------------------------------------------------------------------
// Kernel B2: checkpoint deltas (parallel; proven R15).
// ---------------------------------------------------------------------------
__global__ __launch_bounds__(256) void delta_kernel(
    const float* __restrict__ u,
    const float* __restrict__ e1s,
    const float* __restrict__ g2s,
    const float* __restrict__ dz2s,
    float* __restrict__ snapW,   // [64][64][256]
    float* __restrict__ snapB1,  // [64][256]
    float* __restrict__ snapW2,  // [64][256]
    float* __restrict__ snapB2)  // [64]
{
    const int b  = blockIdx.x + 1;        // 1..63
    const int s0 = (b - 1) * 128;
    const int j  = threadIdx.x;

    __shared__ __align__(16) float uks[128][64];

    #pragma unroll
    for (int k = 0; k < 8; ++k) {
        int l = k * 256 + j;
        int s = l >> 4, q = l & 15;
        *(float4*)&uks[s][q * 4] =
            *(const float4*)&u[(size_t)(s0 + s) * 128 + 64 + q * 4];
    }
    __syncthreads();

    float acc[64];
    #pragma unroll
    for (int i = 0; i < 64; ++i) acc[i] = 0.f;
    float sB1 = 0.f, sW2 = 0.f, sB2 = 0.f;

    for (int s = 0; s < 128; ++s) {
        float e1v = e1s[(size_t)(s0 + s) * 256 + j];
        float g2v = g2s[(size_t)(s0 + s) * 256 + j];
        sB1 += e1v;
        sW2 += g2v;
        sB2 += dz2s[s0 + s];
        #pragma unroll
        for (int q = 0; q < 16; ++q) {
            float4 uv = *(const float4*)&uks[s][q * 4];
            acc[4*q+0] = fmaf(uv.x, e1v, acc[4*q+0]);
            acc[4*q+1] = fmaf(uv.y, e1v, acc[4*q+1]);
            acc[4*q+2] = fmaf(uv.z, e1v, acc[4*q+2]);
            acc[4*q+3] = fmaf(uv.w, e1v, acc[4*q+3]);
        }
    }

    float* dW = snapW + (size_t)b * 16384;
    #pragma unroll
    for (int i = 0; i < 64; ++i) dW[i * 256 + j] = acc[i];
    snapB1[b * 256 + j] = sB1;
    snapW2[b * 256 + j] = sW2;
    if (j == 0) snapB2[b] = sB2;
}

// ---------------------------------------------------------------------------
// Kernel B3: in-place prefix over checkpoint deltas -> exact snapshots.
// ---------------------------------------------------------------------------
__global__ __launch_bounds__(256) void prefix_kernel(
    const float* __restrict__ W10,
    const float* __restrict__ b10,
    const float* __restrict__ W20,
    const float* __restrict__ b20,
    const float* __restrict__ log_eta,
    float* __restrict__ snapW,
    float* __restrict__ snapB1,
    float* __restrict__ snapW2,
    float* __restrict__ snapB2,
    int NS)
{
    const int i = blockIdx.x;
    const int j = threadIdx.x;
    const float eta = __expf(log_eta[0]);

    float w = W10[i * 256 + j];
    snapW[(size_t)0 * 16384 + i * 256 + j] = w;
    for (int c = 1; c < NS; ++c) {
        float d = snapW[(size_t)c * 16384 + i * 256 + j];
        w -= d;
        snapW[(size_t)c * 16384 + i * 256 + j] = w;
    }

    if (i == 0) {
        float b1 = b10[j];
        float w2 = W20[j];
        snapB1[j] = b1;
        snapW2[j] = w2;
        for (int c = 1; c < NS; ++c) {
            b1 -= snapB1[c * 256 + j];
            w2 -= eta * snapW2[c * 256 + j];
            snapB1[c * 256 + j] = b1;
            snapW2[c * 256 + j] = w2;
        }
        if (j == 0) {
            float b2 = b20[0];
            snapB2[0] = b2;
            for (int c = 1; c < NS; ++c) {
                b2 -= eta * snapB2[c];
                snapB2[c] = b2;
            }
        }
    }
}

// ---------------------------------------------------------------------------
// Kernel C: parallel scores reconstruction from 128-step snapshots (R13/R15).
// ---------------------------------------------------------------------------
#define TB 32
__global__ __launch_bounds__(256) void scores_kernel(
    const float* __restrict__ u,
    const float* __restrict__ e1s,
    const float* __restrict__ g2s,
    const float* __restrict__ dz2s,
    const float* __restrict__ snapW,   // [64][64][256]
    const float* __restrict__ snapB1,  // [64][256]
    const float* __restrict__ snapW2,  // [64][256]
    const float* __restrict__ snapB2,  // [64]
    const float* __restrict__ log_eta,
    float* __restrict__ out,
    int T)
{
    const int tid = threadIdx.x;
    const int t0  = blockIdx.x * TB;
    const int j   = tid;
    const int wv  = tid >> 6;
    const int lane = tid & 63;
    const int snapc = t0 >> 7;

    __shared__ __align__(16) float uq[TB][68];
    __shared__ __align__(16) float uk[TB][68];
    __shared__ __align__(16) float Dl[TB][36];
    __shared__ float redl[2][4];

    #pragma unroll
    for (int k = 0; k < 2; ++k) {
        int idx = tid * 2 + k;
        int tl = idx >> 4, c4 = idx & 15;
        *(float4*)&uq[tl][c4 * 4] = *(const float4*)&u[(size_t)(t0 + tl) * 128 + c4 * 4];
    }
    const float eta = __expf(log_eta[0]);
    float w2p = snapW2[snapc * 256 + j];
    float b2p = snapB2[snapc];
    float b1j = snapB1[snapc * 256 + j];
    __syncthreads();

    float acc[TB];
    {
        const float* Wsn = snapW + (size_t)snapc * 16384;
        float wcol[64];
        #pragma unroll
        for (int i = 0; i < 64; ++i) wcol[i] = Wsn[i * DM + j];
        for (int tl = 0; tl < TB; ++tl) {
            float a = b1j;
            #pragma unroll
            for (int q = 0; q < 16; ++q) {
                float4 uv = *(const float4*)&uq[tl][q * 4];
                a = fmaf(uv.x, wcol[4*q+0], a);
                a = fmaf(uv.y, wcol[4*q+1], a);
                a = fmaf(uv.z, wcol[4*q+2], a);
                a = fmaf(uv.w, wcol[4*q+3], a);
            }
            acc[tl] = a;
        }
    }

    const int cs = snapc << 2;
    const int ce = t0 >> 5;
    for (int c = cs; c <= ce; ++c) {
        const int sc = c * TB;
        __syncthreads();
        #pragma unroll
        for (int k = 0; k < 2; ++k) {
            int idx = tid * 2 + k;
            int sl = idx >> 4, c4 = idx & 15;
            *(float4*)&uk[sl][c4 * 4] = *(const float4*)&u[(size_t)(sc + sl) * 128 + 64 + c4 * 4];
        }
        __syncthreads();
        {
            int tl = tid & 31, sg = tid >> 5;
            float4 uqr[16];
            #pragma unroll
            for (int q = 0; q < 16; ++q) uqr[q] = *(const float4*)&uq[tl][q * 4];
            #pragma unroll
            for (int k = 0; k < 4; ++k) {
                int sl = sg * 4 + k;
                float d = 0.f;
                #pragma unroll
                for (int q = 0; q < 16; ++q) {
                    float4 ukr = *(const float4*)&uk[sl][q * 4];
                    d = fmaf(ukr.x, uqr[q].x, d);
                    d = fmaf(ukr.y, uqr[q].y, d);
                    d = fmaf(ukr.z, uqr[q].z, d);
                    d = fmaf(ukr.w, uqr[q].w, d);
                }
                Dl[sl][tl] = d;
            }
        }
        __syncthreads();

        const bool lastc = (c == ce);
        if (!lastc) {
            float e1acc = 0.f;
            for (int sl = 0; sl < TB; ++sl) {
                const int s = sc + sl;
                float e1v = e1s[(size_t)s * 256 + j];
                float g2v = g2s[(size_t)s * 256 + j];
                float dzv = dz2s[s];
                w2p = fmaf(-eta, g2v, w2p);
                b2p = fmaf(-eta, dzv, b2p);
                e1acc += e1v;
                float4 dreg[8];
                #pragma unroll
                for (int q = 0; q < 8; ++q) dreg[q] = *(const float4*)&Dl[sl][q * 4];
                #pragma unroll
                for (int tl = 0; tl < TB; ++tl) {
                    float D = (tl & 2) ? ((tl & 1) ? dreg[tl>>2].w : dreg[tl>>2].z)
                                       : ((tl & 1) ? dreg[tl>>2].y : dreg[tl>>2].x);
                    acc[tl] = fmaf(-e1v, D, acc[tl]);
                }
            }
            #pragma unroll
            for (int tl = 0; tl < TB; ++tl) acc[tl] -= e1acc;
        } else {
            for (int sl = 0; sl < TB; ++sl) {
                const int s = sc + sl;
                float zq = 0.f;
                #pragma unroll
                for (int tl = 0; tl < TB; ++tl) if (tl == sl) zq = acc[tl];
                float tq = tanh_fast(0.79788456f * zq * fmaf(0.044715f, zq*zq, 1.f));
                float aq = 0.5f * zq * (1.f + tq);
                float v  = wave_sum63(aq * w2p);
                if (lane == 63) redl[sl & 1][wv] = v;
                __syncthreads();
                float zs = redl[sl & 1][0] + redl[sl & 1][1] + redl[sl & 1][2] + redl[sl & 1][3] + b2p;
                if (tid == 0) out[t0 + sl] = sigmoid_fast(zs);

                float e1v = e1s[(size_t)s * 256 + j];
                float g2v = g2s[(size_t)s * 256 + j];
                float dzv = dz2s[s];
                w2p = fmaf(-eta, g2v, w2p);
                b2p = fmaf(-eta, dzv, b2p);
                float4 dreg[8];
                #pragma unroll
                for (int q = 0; q < 8; ++q) dreg[q] = *(const float4*)&Dl[sl][q * 4];
                #pragma unroll
                for (int tl = 0; tl < TB; ++tl) {
                    float D = (tl & 2) ? ((tl & 1) ? dreg[tl>>2].w : dreg[tl>>2].z)
                                       : ((tl & 1) ? dreg[tl>>2].y : dreg[tl>>2].x);
                    float e1m = (tl > sl) ? e1v : 0.f;
                    acc[tl] = fmaf(-e1m, D + 1.f, acc[tl]);
                }
            }
        }
    }
}

// ---------------------------------------------------------------------------
// Kernel D: loss = sum (s(t)-C(t))^2
// ---------------------------------------------------------------------------
__global__ __launch_bounds__(256) void loss_kernel(
    const float* __restrict__ C, float* __restrict__ out, int T)
{
    const int tid = threadIdx.x;
    const int wv = tid >> 6, lane = tid & 63;
    __shared__ float part[4];
    float acc = 0.f;
    for (int t = tid; t < T; t += 256) {
        float d = out[t] - C[t];
        acc = fmaf(d, d, acc);
    }
    acc = wave_sum63(acc);
    if (lane == 63) part[wv] = acc;
    __syncthreads();
    if (tid == 0) out[T] = ((part[0] + part[1]) + (part[2] + part[3]));
}

// ---------------------------------------------------------------------------
extern "C" void kernel_launch(void* const* d_in, const int* in_sizes, int n_in,
                              void* d_out, int out_size, void* d_ws, size_t ws_size,
                              hipStream_t stream) {
    const float* phi     = (const float*)d_in[0];
    const float* C_seq   = (const float*)d_in[1];
    const float* thK     = (const float*)d_in[2];
    const float* thQ     = (const float*)d_in[3];
    const float* W10     = (const float*)d_in[4];
    const float* b10     = (const float*)d_in[5];
    const float* W20     = (const float*)d_in[6];
    const float* b20     = (const float*)d_in[7];
    const float* log_eta = (const float*)d_in[8];

    const int T    = in_sizes[1];          // 8192
    const int dphi = in_sizes[0] / T;      // 4096
    const int NS   = T >> 7;               // 64 snapshots

    char* ws = (char*)d_ws;
    size_t off = 0;
    float*  uw     = (float*)(ws + off);  off += (size_t)T * 128 * 4;     // 4 MB
    float4* dd4    = (float4*)(ws + off); off += (size_t)T * 4 * 4;
    float*  dz2s   = (float*)(ws + off);  off += (size_t)T * 4;
    float*  e1s    = (float*)(ws + off);  off += (size_t)T * 256 * 4;     // 8 MB
    float*  g2s    = (float*)(ws + off);  off += (size_t)T * 256 * 4;     // 8 MB
    float*  snapW  = (float*)(ws + off);  off += (size_t)NS * 16384 * 4;  // 4 MB
    float*  snapB1 = (float*)(ws + off);  off += (size_t)NS * 256 * 4;
    float*  snapW2 = (float*)(ws + off);  off += (size_t)NS * 256 * 4;
    float*  snapB2 = (float*)(ws + off);  off += (size_t)NS * 4;

    proj_kernel<<<T / 32, 256, 0, stream>>>(phi, thK, thQ, uw, dphi);
    dots3_kernel<<<T / 4, 256, 0, stream>>>(uw, dd4, T);
    scan_k2<<<1, 256, 0, stream>>>(uw, dd4, W10, b10, W20, b20, log_eta,
                                   e1s, g2s, dz2s, T);
    delta_kernel<<<NS - 1, 256, 0, stream>>>(uw, e1s, g2s, dz2s,
                                             snapW, snapB1, snapW2, snapB2);
    prefix_kernel<<<64, 256, 0, stream>>>(W10, b10, W20, b20, log_eta,
                                          snapW, snapB1, snapW2, snapB2, NS);
    scores_kernel<<<T / TB, 256, 0, stream>>>(uw, e1s, g2s, dz2s,
                                              snapW, snapB1, snapW2, snapB2,
                                              log_eta, (float*)d_out, T);
    loss_kernel<<<1, 256, 0, stream>>>(C_seq, (float*)d_out, T);
}

// Round 19
// 5448.131 us; speedup vs baseline: 1.0843x; 1.0843x over previous
//
#include <hip/hip_runtime.h>
#include <hip/hip_bf16.h>

#define DH 64
#define DM 256

typedef float f32x2 __attribute__((ext_vector_type(2)));

__device__ __forceinline__ f32x2 sp2(float s) { return (f32x2){s, s}; }
__device__ __forceinline__ f32x2 pkfma(f32x2 a, f32x2 b, f32x2 c) {
#if __has_builtin(__builtin_elementwise_fma)
    return __builtin_elementwise_fma(a, b, c);
#else
    f32x2 r; r.x = fmaf(a.x, b.x, c.x); r.y = fmaf(a.y, b.y, c.y); return r;
#endif
}

__device__ __forceinline__ float tanh_fast(float y) {
    float e = __expf(2.0f * y);
    return 1.0f - 2.0f / (e + 1.0f);
}
__device__ __forceinline__ float sigmoid_fast(float x) {
    return 1.0f / (1.0f + __expf(-x));
}

template <int CTRL, int RMASK>
__device__ __forceinline__ float dpp_term(float x) {
    int p = __builtin_amdgcn_update_dpp(0, __float_as_int(x), CTRL, RMASK, 0xf, false);
    return __int_as_float(p);
}
__device__ __forceinline__ float wave_sum63(float x) {
    x += dpp_term<0xB1,  0xf>(x);
    x += dpp_term<0x4E,  0xf>(x);
    x += dpp_term<0x141, 0xf>(x);
    x += dpp_term<0x140, 0xf>(x);
    x += dpp_term<0x142, 0xa>(x);
    x += dpp_term<0x143, 0xc>(x);
    return x;
}

// ---------------------------------------------------------------------------
// Kernel A: u[t][0..63] = phi[t]·thetaQ, u[t][64..127] = phi[t]·thetaK
// ---------------------------------------------------------------------------
__global__ __launch_bounds__(256) void proj_kernel(
    const float* __restrict__ phi,
    const float* __restrict__ thK,
    const float* __restrict__ thQ,
    float* __restrict__ u,
    int dphi)
{
    const int tid  = threadIdx.x;
    const int th32 = tid & 31;
    const int tt8  = tid >> 5;
    const int t0   = tt8 * 4;
    const int h0   = th32 * 4;
    const int T0   = blockIdx.x * 32;

    __shared__ float sPhiT[32][36];
    __shared__ float sThT[32][128];

    const int h   = tid >> 1;
    const int ko  = (tid & 1) * 16;
    const float* trow = (h < 64) ? (thQ + (size_t)h * dphi)
                                 : (thK + (size_t)(h - 64) * dphi);
    const int tr  = tid >> 3;
    const int k4p = (tid & 7) * 4;

    float4 pv, tv0, tv1, tv2, tv3;
    pv  = *(const float4*)&phi[(size_t)(T0 + tr) * dphi + k4p];
    tv0 = *(const float4*)&trow[ko + 0];
    tv1 = *(const float4*)&trow[ko + 4];
    tv2 = *(const float4*)&trow[ko + 8];
    tv3 = *(const float4*)&trow[ko + 12];

    float acc[4][4];
    #pragma unroll
    for (int i = 0; i < 4; ++i)
        #pragma unroll
        for (int jj = 0; jj < 4; ++jj) acc[i][jj] = 0.0f;

    const int NC = dphi / 32;
    for (int c = 0; c < NC; ++c) {
        __syncthreads();
        sPhiT[k4p + 0][tr] = pv.x;
        sPhiT[k4p + 1][tr] = pv.y;
        sPhiT[k4p + 2][tr] = pv.z;
        sPhiT[k4p + 3][tr] = pv.w;
        sThT[ko +  0][h] = tv0.x;  sThT[ko +  1][h] = tv0.y;
        sThT[ko +  2][h] = tv0.z;  sThT[ko +  3][h] = tv0.w;
        sThT[ko +  4][h] = tv1.x;  sThT[ko +  5][h] = tv1.y;
        sThT[ko +  6][h] = tv1.z;  sThT[ko +  7][h] = tv1.w;
        sThT[ko +  8][h] = tv2.x;  sThT[ko +  9][h] = tv2.y;
        sThT[ko + 10][h] = tv2.z;  sThT[ko + 11][h] = tv2.w;
        sThT[ko + 12][h] = tv3.x;  sThT[ko + 13][h] = tv3.y;
        sThT[ko + 14][h] = tv3.z;  sThT[ko + 15][h] = tv3.w;
        __syncthreads();
        if (c + 1 < NC) {
            const int kb = (c + 1) * 32;
            pv  = *(const float4*)&phi[(size_t)(T0 + tr) * dphi + kb + k4p];
            tv0 = *(const float4*)&trow[kb + ko + 0];
            tv1 = *(const float4*)&trow[kb + ko + 4];
            tv2 = *(const float4*)&trow[kb + ko + 8];
            tv3 = *(const float4*)&trow[kb + ko + 12];
        }
        #pragma unroll 8
        for (int k = 0; k < 32; ++k) {
            float4 ph = *(const float4*)&sPhiT[k][t0];
            float4 th = *(const float4*)&sThT[k][h0];
            acc[0][0] = fmaf(ph.x, th.x, acc[0][0]);
            acc[0][1] = fmaf(ph.x, th.y, acc[0][1]);
            acc[0][2] = fmaf(ph.x, th.z, acc[0][2]);
            acc[0][3] = fmaf(ph.x, th.w, acc[0][3]);
            acc[1][0] = fmaf(ph.y, th.x, acc[1][0]);
            acc[1][1] = fmaf(ph.y, th.y, acc[1][1]);
            acc[1][2] = fmaf(ph.y, th.z, acc[1][2]);
            acc[1][3] = fmaf(ph.y, th.w, acc[1][3]);
            acc[2][0] = fmaf(ph.z, th.x, acc[2][0]);
            acc[2][1] = fmaf(ph.z, th.y, acc[2][1]);
            acc[2][2] = fmaf(ph.z, th.z, acc[2][2]);
            acc[2][3] = fmaf(ph.z, th.w, acc[2][3]);
            acc[3][0] = fmaf(ph.w, th.x, acc[3][0]);
            acc[3][1] = fmaf(ph.w, th.y, acc[3][1]);
            acc[3][2] = fmaf(ph.w, th.z, acc[3][2]);
            acc[3][3] = fmaf(ph.w, th.w, acc[3][3]);
        }
    }
    #pragma unroll
    for (int i = 0; i < 4; ++i) {
        float4 o;
        o.x = acc[i][0]; o.y = acc[i][1]; o.z = acc[i][2]; o.w = acc[i][3];
        *(float4*)&u[(size_t)(T0 + t0 + i) * 128 + h0] = o;
    }
}

// ---------------------------------------------------------------------------
// Kernel A2: dd2[t] = { uk(t-1)·uk(t), uk(t-2)·uk(t) }   (zeros at edges)
// ---------------------------------------------------------------------------
__global__ __launch_bounds__(256) void dots2_kernel(
    const float* __restrict__ u, float2* __restrict__ dd2, int T)
{
    const int t    = (blockIdx.x * 256 + threadIdx.x) >> 6;
    const int lane = threadIdx.x & 63;
    if (t >= T) return;
    float ukt = u[(size_t)t * 128 + 64 + lane];
    float k1 = (t >= 1) ? u[(size_t)(t - 1) * 128 + 64 + lane] : 0.f;
    float k2 = (t >= 2) ? u[(size_t)(t - 2) * 128 + 64 + lane] : 0.f;
    float p1 = k1 * ukt, p2 = k2 * ukt;
    #pragma unroll
    for (int off = 32; off > 0; off >>= 1) {
        p1 += __shfl_xor(p1, off);
        p2 += __shfl_xor(p2, off);
    }
    if (lane == 0) dd2[t] = make_float2(p1, p2);
}

// ---------------------------------------------------------------------------
// Kernel B: 4-wave k-only TTT scan — EXACT R10 structure (measured 5104 us).
// No snapshot work inside; emits e1s/g2s/dz2s streams only.
// ---------------------------------------------------------------------------
__global__ __launch_bounds__(256, 1) void scan_k4(
    const float* __restrict__ u,       // [T][128]
    const float2* __restrict__ dd2g,   // [T]
    const float* __restrict__ W10,     // [64][256]
    const float* __restrict__ b10,     // [256]
    const float* __restrict__ W20,     // [256]
    const float* __restrict__ b20,
    const float* __restrict__ log_eta,
    float* __restrict__ e1s,           // [T][256]
    float* __restrict__ g2s,           // [T][256]
    float* __restrict__ dz2s,          // [T]
    int T)
{
    const int j    = threadIdx.x;
    const int lane = j & 63;
    const int wv   = j >> 6;
    const int uko  = 16 * wv;

    __shared__ __align__(16) float  ubuf[2][64][68];
    __shared__ __align__(16) float  pbuf[2][4][256];
    __shared__ __align__(16) float  ebufT[4][4][72];
    __shared__ __align__(16) float  pqk[2][4];
    __shared__ __align__(16) float2 dbuf[2][64];

    const int NB = T >> 6;
    const int sl = j >> 2, qq = j & 3;

    {
        const float* src = u + (size_t)sl * 128 + 64 + qq * 16;
        #pragma unroll
        for (int k = 0; k < 4; ++k)
            *(float4*)&ubuf[0][sl][qq * 16 + k * 4] = *(const float4*)&src[k * 4];
        if (j < 64) dbuf[0][j] = dd2g[j];
        if (j < 4)  pqk[1][j] = -2.5e29f;
        float* ez = &ebufT[2][0][0];
        for (int k = j; k < 2 * 4 * 72; k += 256) ez[k] = 0.f;
    }

    f32x2 w1p[32];
    #pragma unroll
    for (int i = 0; i < 16; ++i) {
        float4 wr = *(const float4*)&W10[(uko + i) * DM + lane * 4];
        w1p[2 * i]     = (f32x2){wr.x, wr.y};
        w1p[2 * i + 1] = (f32x2){wr.z, wr.w};
    }
    float b1j = b10[j];
    float w2j = W20[j];
    float b2  = b20[0];
    const float eta = __expf(log_eta[0]);
    float dZ2p = 0.f, en1 = 0.f, en2 = 0.f, x2p = 0.f;

    __syncthreads();

    {
        const float* ur0 = &ubuf[0][0][uko];
        f32x2 a0 = sp2(0.f), a1 = sp2(0.f);
        #pragma unroll
        for (int q = 0; q < 4; ++q) {
            float4 us = *(const float4*)&ur0[q * 4];
            a0 = pkfma(sp2(us.x), w1p[8*q+0], a0); a1 = pkfma(sp2(us.x), w1p[8*q+1], a1);
            a0 = pkfma(sp2(us.y), w1p[8*q+2], a0); a1 = pkfma(sp2(us.y), w1p[8*q+3], a1);
            a0 = pkfma(sp2(us.z), w1p[8*q+4], a0); a1 = pkfma(sp2(us.z), w1p[8*q+5], a1);
            a0 = pkfma(sp2(us.w), w1p[8*q+6], a0); a1 = pkfma(sp2(us.w), w1p[8*q+7], a1);
        }
        float4 wk; wk.x = a0.x; wk.y = a0.y; wk.z = a1.x; wk.w = a1.y;
        *(float4*)&pbuf[0][wv][lane * 4] = wk;
    }
    __syncthreads();

    float4 st[4];
    float2 std2 = make_float2(0.f, 0.f);

    for (int t = 0; t < T; ++t) {
        const int r   = t & 63;
        const int B   = t >> 6;
        const int bs  = B & 1;
        const int pbR = t & 1;

        float4 pqK = *(const float4*)&pqk[pbR ^ 1][0];
        const int sE = (t + 2) & 3;
        float eb0 = ebufT[sE][0][lane];
        float eb1 = ebufT[sE][1][lane];
        float eb2 = ebufT[sE][2][lane];
        float eb3 = ebufT[sE][3][lane];
        float2 dd = dbuf[bs][r];
        float pB0 = pbuf[pbR][0][j], pB1 = pbuf[pbR][1][j];
        float pB2 = pbuf[pbR][2][j], pB3 = pbuf[pbR][3][j];
        const int rn = (t + 1 < T) ? t + 1 : T - 1;
        const int rm = (t >= 2) ? t - 2 : 0;
        const float* urN = &ubuf[(rn >> 6) & 1][rn & 63][uko];
        const float* urM = &ubuf[(rm >> 6) & 1][rm & 63][uko];
        float4 n0 = *(const float4*)&urN[0],  n1 = *(const float4*)&urN[4];
        float4 n2 = *(const float4*)&urN[8],  n3 = *(const float4*)&urN[12];
        float4 m0 = *(const float4*)&urM[0],  m1 = *(const float4*)&urM[4];
        float4 m2 = *(const float4*)&urM[8],  m3 = *(const float4*)&urM[12];

        float zp   = ((pqK.x + pqK.y) + (pqK.z + pqK.w)) + b2;
        float pred = sigmoid_fast(zp);
        float dZ2  = 2.f * pred * pred * (1.f - pred);
        float e1o  = dZ2 * en1;
        if (t > 0) {
            e1s[(size_t)(t - 1) * 256 + j] = e1o;
            g2s[(size_t)(t - 1) * 256 + j] = dZ2 * x2p;
            if (j == 0) dz2s[t - 1] = dZ2;
        }

        f32x2 e1g0 = sp2(dZ2p) * (f32x2){eb0, eb1};
        f32x2 e1g1 = sp2(dZ2p) * (f32x2){eb2, eb3};
        f32x2 a0 = sp2(0.f), a1 = sp2(0.f);
#define ROWK(ib, ums, uns) {                                   \
        f32x2 wa = pkfma(sp2(-(ums)), e1g0, w1p[ib]);          \
        f32x2 wb = pkfma(sp2(-(ums)), e1g1, w1p[(ib) + 1]);    \
        w1p[ib] = wa; w1p[(ib) + 1] = wb;                      \
        a0 = pkfma(sp2(uns), wa, a0);                          \
        a1 = pkfma(sp2(uns), wb, a1); }
        ROWK(0,  m0.x, n0.x); ROWK(2,  m0.y, n0.y);
        ROWK(4,  m0.z, n0.z); ROWK(6,  m0.w, n0.w);
        ROWK(8,  m1.x, n1.x); ROWK(10, m1.y, n1.y);
        ROWK(12, m1.z, n1.z); ROWK(14, m1.w, n1.w);
        ROWK(16, m2.x, n2.x); ROWK(18, m2.y, n2.y);
        ROWK(20, m2.z, n2.z); ROWK(22, m2.w, n2.w);
        ROWK(24, m3.x, n3.x); ROWK(26, m3.y, n3.y);
        ROWK(28, m3.z, n3.z); ROWK(30, m3.w, n3.w);
#undef ROWK
        { float4 wk; wk.x = a0.x; wk.y = a0.y; wk.z = a1.x; wk.w = a1.y;
          *(float4*)&pbuf[pbR ^ 1][wv][lane * 4] = wk; }

        float e1o2 = dZ2p * en2;
        b1j -= e1o;
        w2j  = fmaf(-eta * dZ2, x2p, w2j);
        b2  -= eta * dZ2;
        float Pk = ((pB0 + pB1) + (pB2 + pB3));
        float zk = Pk + b1j - e1o2 * dd.y - e1o * dd.x;
        float tk = tanh_fast(0.79788456f * zk * fmaf(0.044715f, zk * zk, 1.f));
        float x2 = 0.5f * zk * (1.f + tk);
        float gb = 0.5f * zk * ((1.f - tk * tk) *
                   fmaf(0.1070322243f, zk * zk, 0.79788456f))
                 + 0.5f * (1.f + tk);
        float en = eta * w2j * gb;
        ebufT[t & 3][j & 3][j >> 2] = en;
        float pk = wave_sum63(x2 * w2j);
        if (lane == 63) pqk[t & 1][wv] = pk;

        dZ2p = dZ2; en2 = en1; en1 = en; x2p = x2;

        if (r == 0 && B + 1 < NB) {
            const float* src = u + (size_t)((B + 1) * 64 + sl) * 128 + 64 + qq * 16;
            #pragma unroll
            for (int k = 0; k < 4; ++k) st[k] = *(const float4*)&src[k * 4];
            if (j < 64) std2 = dd2g[(B + 1) * 64 + j];
        }
        if (r == 32 && B + 1 < NB) {
            #pragma unroll
            for (int k = 0; k < 4; ++k)
                *(float4*)&ubuf[bs ^ 1][sl][qq * 16 + k * 4] = st[k];
            if (j < 64) dbuf[bs ^ 1][j] = std2;
        }

        asm volatile("s_waitcnt lgkmcnt(0)" ::: "memory");
        __builtin_amdgcn_s_barrier();
        asm volatile("" ::: "memory");
    }

    {
        float4 pqK = *(const float4*)&pqk[(T - 1) & 1][0];
        float zp   = ((pqK.x + pqK.y) + (pqK.z + pqK.w)) + b2;
        float pred = sigmoid_fast(zp);
        float dZ2  = 2.f * pred * pred * (1.f - pred);
        e1s[(size_t)(T - 1) * 256 + j] = dZ2 * en1;
        g2s[(size_t)(T - 1) * 256 + j] = dZ2 * x2p;
        if (j == 0) dz2s[T - 1] = dZ2;
    }
}

// ---------------------------------------------------------------------------
// Kernel B2: checkpoint deltas (parallel; proven R15).
// ---------------------------------------------------------------------------
__global__ __launch_bounds__(256) void delta_kernel(
    const float* __restrict__ u,
    const float* __restrict__ e1s,
    const float* __restrict__ g2s,
    const float* __restrict__ dz2s,
    float* __restrict__ snapW,   // [64][64][256]
    float* __restrict__ snapB1,  // [64][256]
    float* __restrict__ snapW2,  // [64][256]
    float* __restrict__ snapB2)  // [64]
{
    const int b  = blockIdx.x + 1;        // 1..63
    const int s0 = (b - 1) * 128;
    const int j  = threadIdx.x;

    __shared__ __align__(16) float uks[128][64];

    #pragma unroll
    for (int k = 0; k < 8; ++k) {
        int l = k * 256 + j;
        int s = l >> 4, q = l & 15;
        *(float4*)&uks[s][q * 4] =
            *(const float4*)&u[(size_t)(s0 + s) * 128 + 64 + q * 4];
    }
    __syncthreads();

    float acc[64];
    #pragma unroll
    for (int i = 0; i < 64; ++i) acc[i] = 0.f;
    float sB1 = 0.f, sW2 = 0.f, sB2 = 0.f;

    for (int s = 0; s < 128; ++s) {
        float e1v = e1s[(size_t)(s0 + s) * 256 + j];
        float g2v = g2s[(size_t)(s0 + s) * 256 + j];
        sB1 += e1v;
        sW2 += g2v;
        sB2 += dz2s[s0 + s];
        #pragma unroll
        for (int q = 0; q < 16; ++q) {
            float4 uv = *(const float4*)&uks[s][q * 4];
            acc[4*q+0] = fmaf(uv.x, e1v, acc[4*q+0]);
            acc[4*q+1] = fmaf(uv.y, e1v, acc[4*q+1]);
            acc[4*q+2] = fmaf(uv.z, e1v, acc[4*q+2]);
            acc[4*q+3] = fmaf(uv.w, e1v, acc[4*q+3]);
        }
    }

    float* dW = snapW + (size_t)b * 16384;
    #pragma unroll
    for (int i = 0; i < 64; ++i) dW[i * 256 + j] = acc[i];
    snapB1[b * 256 + j] = sB1;
    snapW2[b * 256 + j] = sW2;
    if (j == 0) snapB2[b] = sB2;
}

// ---------------------------------------------------------------------------
// Kernel B3: in-place prefix over checkpoint deltas -> exact snapshots.
// ---------------------------------------------------------------------------
__global__ __launch_bounds__(256) void prefix_kernel(
    const float* __restrict__ W10,
    const float* __restrict__ b10,
    const float* __restrict__ W20,
    const float* __restrict__ b20,
    const float* __restrict__ log_eta,
    float* __restrict__ snapW,
    float* __restrict__ snapB1,
    float* __restrict__ snapW2,
    float* __restrict__ snapB2,
    int NS)
{
    const int i = blockIdx.x;
    const int j = threadIdx.x;
    const float eta = __expf(log_eta[0]);

    float w = W10[i * 256 + j];
    snapW[(size_t)0 * 16384 + i * 256 + j] = w;
    for (int c = 1; c < NS; ++c) {
        float d = snapW[(size_t)c * 16384 + i * 256 + j];
        w -= d;
        snapW[(size_t)c * 16384 + i * 256 + j] = w;
    }

    if (i == 0) {
        float b1 = b10[j];
        float w2 = W20[j];
        snapB1[j] = b1;
        snapW2[j] = w2;
        for (int c = 1; c < NS; ++c) {
            b1 -= snapB1[c * 256 + j];
            w2 -= eta * snapW2[c * 256 + j];
            snapB1[c * 256 + j] = b1;
            snapW2[c * 256 + j] = w2;
        }
        if (j == 0) {
            float b2 = b20[0];
            snapB2[0] = b2;
            for (int c = 1; c < NS; ++c) {
                b2 -= eta * snapB2[c];
                snapB2[c] = b2;
            }
        }
    }
}

// ---------------------------------------------------------------------------
// Kernel C: parallel scores reconstruction from 128-step snapshots (R13/R15).
// ---------------------------------------------------------------------------
#define TB 32
__global__ __launch_bounds__(256) void scores_kernel(
    const float* __restrict__ u,
    const float* __restrict__ e1s,
    const float* __restrict__ g2s,
    const float* __restrict__ dz2s,
    const float* __restrict__ snapW,   // [64][64][256]
    const float* __restrict__ snapB1,  // [64][256]
    const float* __restrict__ snapW2,  // [64][256]
    const float* __restrict__ snapB2,  // [64]
    const float* __restrict__ log_eta,
    float* __restrict__ out,
    int T)
{
    const int tid = threadIdx.x;
    const int t0  = blockIdx.x * TB;
    const int j   = tid;
    const int wv  = tid >> 6;
    const int lane = tid & 63;
    const int snapc = t0 >> 7;

    __shared__ __align__(16) float uq[TB][68];
    __shared__ __align__(16) float uk[TB][68];
    __shared__ __align__(16) float Dl[TB][36];
    __shared__ float redl[2][4];

    #pragma unroll
    for (int k = 0; k < 2; ++k) {
        int idx = tid * 2 + k;
        int tl = idx >> 4, c4 = idx & 15;
        *(float4*)&uq[tl][c4 * 4] = *(const float4*)&u[(size_t)(t0 + tl) * 128 + c4 * 4];
    }
    const float eta = __expf(log_eta[0]);
    float w2p = snapW2[snapc * 256 + j];
    float b2p = snapB2[snapc];
    float b1j = snapB1[snapc * 256 + j];
    __syncthreads();

    float acc[TB];
    {
        const float* Wsn = snapW + (size_t)snapc * 16384;
        float wcol[64];
        #pragma unroll
        for (int i = 0; i < 64; ++i) wcol[i] = Wsn[i * DM + j];
        for (int tl = 0; tl < TB; ++tl) {
            float a = b1j;
            #pragma unroll
            for (int q = 0; q < 16; ++q) {
                float4 uv = *(const float4*)&uq[tl][q * 4];
                a = fmaf(uv.x, wcol[4*q+0], a);
                a = fmaf(uv.y, wcol[4*q+1], a);
                a = fmaf(uv.z, wcol[4*q+2], a);
                a = fmaf(uv.w, wcol[4*q+3], a);
            }
            acc[tl] = a;
        }
    }

    const int cs = snapc << 2;
    const int ce = t0 >> 5;
    for (int c = cs; c <= ce; ++c) {
        const int sc = c * TB;
        __syncthreads();
        #pragma unroll
        for (int k = 0; k < 2; ++k) {
            int idx = tid * 2 + k;
            int sl = idx >> 4, c4 = idx & 15;
            *(float4*)&uk[sl][c4 * 4] = *(const float4*)&u[(size_t)(sc + sl) * 128 + 64 + c4 * 4];
        }
        __syncthreads();
        {
            int tl = tid & 31, sg = tid >> 5;
            float4 uqr[16];
            #pragma unroll
            for (int q = 0; q < 16; ++q) uqr[q] = *(const float4*)&uq[tl][q * 4];
            #pragma unroll
            for (int k = 0; k < 4; ++k) {
                int sl = sg * 4 + k;
                float d = 0.f;
                #pragma unroll
                for (int q = 0; q < 16; ++q) {
                    float4 ukr = *(const float4*)&uk[sl][q * 4];
                    d = fmaf(ukr.x, uqr[q].x, d);
                    d = fmaf(ukr.y, uqr[q].y, d);
                    d = fmaf(ukr.z, uqr[q].z, d);
                    d = fmaf(ukr.w, uqr[q].w, d);
                }
                Dl[sl][tl] = d;
            }
        }
        __syncthreads();

        const bool lastc = (c == ce);
        if (!lastc) {
            float e1acc = 0.f;
            for (int sl = 0; sl < TB; ++sl) {
                const int s = sc + sl;
                float e1v = e1s[(size_t)s * 256 + j];
                float g2v = g2s[(size_t)s * 256 + j];
                float dzv = dz2s[s];
                w2p = fmaf(-eta, g2v, w2p);
                b2p = fmaf(-eta, dzv, b2p);
                e1acc += e1v;
                float4 dreg[8];
                #pragma unroll
                for (int q = 0; q < 8; ++q) dreg[q] = *(const float4*)&Dl[sl][q * 4];
                #pragma unroll
                for (int tl = 0; tl < TB; ++tl) {
                    float D = (tl & 2) ? ((tl & 1) ? dreg[tl>>2].w : dreg[tl>>2].z)
                                       : ((tl & 1) ? dreg[tl>>2].y : dreg[tl>>2].x);
                    acc[tl] = fmaf(-e1v, D, acc[tl]);
                }
            }
            #pragma unroll
            for (int tl = 0; tl < TB; ++tl) acc[tl] -= e1acc;
        } else {
            for (int sl = 0; sl < TB; ++sl) {
                const int s = sc + sl;
                float zq = 0.f;
                #pragma unroll
                for (int tl = 0; tl < TB; ++tl) if (tl == sl) zq = acc[tl];
                float tq = tanh_fast(0.79788456f * zq * fmaf(0.044715f, zq*zq, 1.f));
                float aq = 0.5f * zq * (1.f + tq);
                float v  = wave_sum63(aq * w2p);
                if (lane == 63) redl[sl & 1][wv] = v;
                __syncthreads();
                float zs = redl[sl & 1][0] + redl[sl & 1][1] + redl[sl & 1][2] + redl[sl & 1][3] + b2p;
                if (tid == 0) out[t0 + sl] = sigmoid_fast(zs);

                float e1v = e1s[(size_t)s * 256 + j];
                float g2v = g2s[(size_t)s * 256 + j];
                float dzv = dz2s[s];
                w2p = fmaf(-eta, g2v, w2p);
                b2p = fmaf(-eta, dzv, b2p);
                float4 dreg[8];
                #pragma unroll
                for (int q = 0; q < 8; ++q) dreg[q] = *(const float4*)&Dl[sl][q * 4];
                #pragma unroll
                for (int tl = 0; tl < TB; ++tl) {
                    float D = (tl & 2) ? ((tl & 1) ? dreg[tl>>2].w : dreg[tl>>2].z)
                                       : ((tl & 1) ? dreg[tl>>2].y : dreg[tl>>2].x);
                    float e1m = (tl > sl) ? e1v : 0.f;
                    acc[tl] = fmaf(-e1m, D + 1.f, acc[tl]);
                }
            }
        }
    }
}

// ---------------------------------------------------------------------------
// Kernel D: loss = sum (s(t)-C(t))^2
// ---------------------------------------------------------------------------
__global__ __launch_bounds__(256) void loss_kernel(
    const float* __restrict__ C, float* __restrict__ out, int T)
{
    const int tid = threadIdx.x;
    const int wv = tid >> 6, lane = tid & 63;
    __shared__ float part[4];
    float acc = 0.f;
    for (int t = tid; t < T; t += 256) {
        float d = out[t] - C[t];
        acc = fmaf(d, d, acc);
    }
    acc = wave_sum63(acc);
    if (lane == 63) part[wv] = acc;
    __syncthreads();
    if (tid == 0) out[T] = ((part[0] + part[1]) + (part[2] + part[3]));
}

// ---------------------------------------------------------------------------
extern "C" void kernel_launch(void* const* d_in, const int* in_sizes, int n_in,
                              void* d_out, int out_size, void* d_ws, size_t ws_size,
                              hipStream_t stream) {
    const float* phi     = (const float*)d_in[0];
    const float* C_seq   = (const float*)d_in[1];
    const float* thK     = (const float*)d_in[2];
    const float* thQ     = (const float*)d_in[3];
    const float* W10     = (const float*)d_in[4];
    const float* b10     = (const float*)d_in[5];
    const float* W20     = (const float*)d_in[6];
    const float* b20     = (const float*)d_in[7];
    const float* log_eta = (const float*)d_in[8];

    const int T    = in_sizes[1];          // 8192
    const int dphi = in_sizes[0] / T;      // 4096
    const int NS   = T >> 7;               // 64 snapshots

    char* ws = (char*)d_ws;
    size_t off = 0;
    float*  uw     = (float*)(ws + off);  off += (size_t)T * 128 * 4;     // 4 MB
    float2* dd2    = (float2*)(ws + off); off += (size_t)T * 2 * 4;
    float*  dz2s   = (float*)(ws + off);  off += (size_t)T * 4;
    float*  e1s    = (float*)(ws + off);  off += (size_t)T * 256 * 4;     // 8 MB
    float*  g2s    = (float*)(ws + off);  off += (size_t)T * 256 * 4;     // 8 MB
    float*  snapW  = (float*)(ws + off);  off += (size_t)NS * 16384 * 4;  // 4 MB
    float*  snapB1 = (float*)(ws + off);  off += (size_t)NS * 256 * 4;
    float*  snapW2 = (float*)(ws + off);  off += (size_t)NS * 256 * 4;
    float*  snapB2 = (float*)(ws + off);  off += (size_t)NS * 4;

    proj_kernel<<<T / 32, 256, 0, stream>>>(phi, thK, thQ, uw, dphi);
    dots2_kernel<<<T / 4, 256, 0, stream>>>(uw, dd2, T);
    scan_k4<<<1, 256, 0, stream>>>(uw, dd2, W10, b10, W20, b20, log_eta,
                                   e1s, g2s, dz2s, T);
    delta_kernel<<<NS - 1, 256, 0, stream>>>(uw, e1s, g2s, dz2s,
                                             snapW, snapB1, snapW2, snapB2);
    prefix_kernel<<<64, 256, 0, stream>>>(W10, b10, W20, b20, log_eta,
                                          snapW, snapB1, snapW2, snapB2, NS);
    scores_kernel<<<T / TB, 256, 0, stream>>>(uw, e1s, g2s, dz2s,
                                              snapW, snapB1, snapW2, snapB2,
                                              log_eta, (float*)d_out, T);
    loss_kernel<<<1, 256, 0, stream>>>(C_seq, (float*)d_out, T);
}